// Round 14
// baseline (594.103 us; speedup 1.0000x reference)
//
#include <hip/hip_runtime.h>
#include <hip/hip_bf16.h>

#define WIDTH_ 2560
#define LRU_   2560
#define HEADS_ 8
#define BW_    320
#define DCONV_ 4
#define BB     4
#define LL     2048
#define MROWS  (BB*LL)          // 8192
#define NCH    32               // scan chunks
#define CLEN   (LL/NCH)         // 64

typedef unsigned short ushort_t;
typedef __attribute__((ext_vector_type(8))) short short8;
typedef __attribute__((ext_vector_type(4))) float f32x4;

__device__ __forceinline__ unsigned short f2bf(float f) {
  union { float f; unsigned u; } v; v.f = f;
  unsigned r = v.u + 0x7fffu + ((v.u >> 16) & 1u);
  return (unsigned short)(r >> 16);
}
__device__ __forceinline__ float bf2f(unsigned short h) {
  union { unsigned u; float f; } v; v.u = ((unsigned)h) << 16;
  return v.f;
}
__device__ __forceinline__ void async_load16(const void* g, void* l) {
  __builtin_amdgcn_global_load_lds(
      (const __attribute__((address_space(1))) unsigned*)g,
      (__attribute__((address_space(3))) unsigned*)l, 16, 0, 0);
}
__device__ __forceinline__ float sigmoidf_(float x) {
  return 1.f / (1.f + __expf(-x));
}
// packed [C/8][PL][8] address (ushort units)
__device__ __forceinline__ size_t pkaddr(int e, int m, int PL) {
  return ((size_t)(e >> 3) * PL + m) * 8 + (e & 7);
}

// ------------- transpose-pack: f32 [R][C] -> bf16 packed [C/8][PL][8] @ row RO -----
// src2 != nullptr: blockIdx.z selects {src, src2} with RO = z*R (Wx/Wy merge)
__global__ void tp_pack(const float* __restrict__ src, const float* __restrict__ src2,
                        ushort_t* __restrict__ dst, int R, int C, int PL, int RO) {
  __shared__ float tile[64][65];
  const int z = blockIdx.z;
  const float* s = (z == 0) ? src : src2;
  const int ro = RO + z * R;
  const int r0 = blockIdx.x * 64, c0 = blockIdx.y * 64;
  const int t = threadIdx.x;
#pragma unroll
  for (int it = 0; it < 4; ++it) {
    int row = it * 16 + (t >> 4);
    int col = (t & 15) * 4;
    *(float4*)&tile[row][col] = *(const float4*)&s[(size_t)(r0 + row) * C + c0 + col];
  }
  __syncthreads();
#pragma unroll
  for (int it = 0; it < 2; ++it) {
    int c8 = it * 4 + (t >> 6);     // 0..7
    int m  = t & 63;
    ushort_t o[8];
#pragma unroll
    for (int j = 0; j < 8; ++j) o[j] = f2bf(tile[m][c8 * 8 + j]);
    *(short8*)&dst[((size_t)(c0 / 8 + c8) * PL + ro + r0 + m) * 8] = *(short8*)o;
  }
}

// prep: gate weights pack (both) + ctab.  dst[h*40+k>>3][RO+n][k&7] = w[h][k][n]
__global__ void prep_kernel(const float* __restrict__ gxw, const float* __restrict__ gaw,
                            ushort_t* __restrict__ dst,
                            const float* __restrict__ apar, float* __restrict__ ctab) {
  const int n_ = HEADS_ * BW_ * BW_;
  int i = blockIdx.x * blockDim.x + threadIdx.x;
  if (i < 2 * n_) {
    const float* w = (i < n_) ? gxw : gaw;
    int RO = (i < n_) ? 0 : BW_;
    int j = (i < n_) ? i : i - n_;
    int n = j % BW_;
    int k = (j / BW_) % BW_;
    int h = j / (BW_ * BW_);
    dst[((size_t)(h * 40 + (k >> 3)) * 640 + RO + n) * 8 + (k & 7)] =
        f2bf(w[((size_t)h * BW_ + k) * BW_ + n]);
  } else if (i < 2 * n_ + LRU_) {
    int e = i - 2 * n_;
    float ap = apar[e];
    float sp = (ap > 15.f) ? ap : log1pf(expf(ap));
    ctab[e] = -8.f * sp;
  }
}

// ============ 256xBN GEMM, packed operands, 8-phase schedule (FROZEN) ============
#define STG_A(KT, H, BUF) do { \
  _Pragma("unroll") for (int u_ = 0; u_ < 2; ++u_) \
    async_load16(Ach + aoff[u_] + (size_t)(KT) * aKt + (H) * 2048, \
                 smem + ((BUF) * 2 + (H)) * 16384 + ldst[u_]); } while (0)
#define STG_B(KT, PART, BUF) do { \
  _Pragma("unroll") for (int u_ = (PART) ? 2 : 0; u_ < ((PART) ? NF : 2); ++u_) \
    async_load16(Bch + boff[u_] + (size_t)(KT) * bKt, \
                 smem + 65536 + (BUF) * BREG + bldst[u_]); } while (0)

#define PHASE(BUF, Q, STAGE_STMT, VMN) do { \
  __builtin_amdgcn_sched_barrier(0); \
  const char* Ah_ = smem + ((BUF) * 2 + wr) * 16384; \
  const char* Bh_ = smem + 65536 + (BUF) * BREG; \
  if ((Q) == 0) { \
    _Pragma("unroll") for (int nf = 0; nf < NF; ++nf) \
      _Pragma("unroll") for (int s = 0; s < 2; ++s) \
        bfr[nf][s] = *(const short8*)(Bh_ + (((s * 4 + l4) * BN) + wc * (BN / 4) + nf * 16 + l15) * 16); \
  } \
  short8 a_[2][2]; \
  _Pragma("unroll") for (int mm = 0; mm < 2; ++mm) \
    _Pragma("unroll") for (int s = 0; s < 2; ++s) \
      a_[mm][s] = *(const short8*)(Ah_ + ((s * 4 + l4) * 128 + ((Q) * 2 + mm) * 16 + l15) * 16); \
  STAGE_STMT; \
  __builtin_amdgcn_sched_barrier(0); \
  __builtin_amdgcn_s_barrier(); \
  asm volatile("s_waitcnt lgkmcnt(0)" ::: "memory"); \
  __builtin_amdgcn_sched_barrier(0); \
  __builtin_amdgcn_s_setprio(1); \
  _Pragma("unroll") for (int mm = 0; mm < 2; ++mm) \
    _Pragma("unroll") for (int nf = 0; nf < NF; ++nf) \
      _Pragma("unroll") for (int s = 0; s < 2; ++s) \
        acc[(Q) * 2 + mm][nf] = __builtin_amdgcn_mfma_f32_16x16x32_bf16( \
            a_[mm][s], bfr[nf][s], acc[(Q) * 2 + mm][nf], 0, 0, 0); \
  __builtin_amdgcn_s_setprio(0); \
  if ((VMN) == 5)      asm volatile("s_waitcnt vmcnt(5)" ::: "memory"); \
  else if ((VMN) == 4) asm volatile("s_waitcnt vmcnt(4)" ::: "memory"); \
  else if ((VMN) == 0) asm volatile("s_waitcnt vmcnt(0)" ::: "memory"); \
  __builtin_amdgcn_sched_barrier(0); \
  __builtin_amdgcn_s_barrier(); \
} while (0)

// EPI 0: f32 row-major store + bias   EPI 1: split packed bf16 (col<2560->C0+bias, else C1)
template<int EPI, int BN>
__global__ __launch_bounds__(512, 2)
void gemm_pk(const ushort_t* __restrict__ A,
             const ushort_t* __restrict__ B, int NPL,
             void* __restrict__ C0, void* __restrict__ C1,
             const float* __restrict__ bias) {
  constexpr int NF = BN / 64;
  constexpr int BREG = BN * 128;
  __shared__ char smem[65536 + 2 * BREG];
  const int tid = threadIdx.x;
  const int lane = tid & 63, w = tid >> 6;
  const int wr = w >> 2, wc = w & 3;
  const int l15 = lane & 15, l4 = lane >> 4;

  const int nblk = gridDim.x;
  const int TN = nblk >> 5;
  const int x8 = blockIdx.x & 7, c = blockIdx.x >> 3;
  const int tm = (x8 * 4 + c / TN) * 256;
  const int tn = (c % TN) * BN;

  const char* Ach = (const char*)A;
  const char* Bch = (const char*)B;
  const size_t aKt = (size_t)8 * MROWS * 16;
  const size_t bKt = (size_t)8 * NPL * 16;

  size_t aoff[2]; int ldst[2];
#pragma unroll
  for (int u = 0; u < 2; ++u) {
    int lb = (u * 512 + tid) * 16;
    int slot = lb >> 11, m = (lb >> 4) & 127;
    aoff[u] = ((size_t)slot * MROWS + tm + m) * 16;
    ldst[u] = lb;
  }
  size_t boff[NF]; int bldst[NF];
#pragma unroll
  for (int u = 0; u < NF; ++u) {
    int lb = (u * 512 + tid) * 16;
    int slot = lb / (BN * 16), n = (lb - slot * (BN * 16)) >> 4;
    boff[u] = ((size_t)slot * NPL + tn + n) * 16;
    bldst[u] = lb;
  }

  f32x4 acc[8][NF] = {};
  short8 bfr[NF][2];

  STG_B(0, 0, 0); STG_B(0, 1, 0);
  STG_A(0, 0, 0); STG_A(0, 1, 0);
  STG_B(1, 0, 1); STG_B(1, 1, 1);
  if (NF == 5) asm volatile("s_waitcnt vmcnt(5)" ::: "memory");
  else         asm volatile("s_waitcnt vmcnt(4)" ::: "memory");
  __builtin_amdgcn_sched_barrier(0);
  __builtin_amdgcn_s_barrier();

#pragma unroll 1
  for (int i = 0; i < 20; ++i) {
    const int k1 = 2 * i + 1, k2 = 2 * i + 2, k3 = 2 * i + 3;
    const bool v2 = (k2 < 40), v3 = (k3 < 40);
    PHASE(0, 0, STG_A(k1, 0, 1), -1);
    PHASE(0, 1, STG_A(k1, 1, 1), -1);
    PHASE(0, 2, if (v2) STG_B(k2, 0, 0), -1);
    PHASE(0, 3, if (v2) STG_B(k2, 1, 0), (v2 ? NF : 0));
    PHASE(1, 0, if (v2) STG_A(k2, 0, 0), -1);
    PHASE(1, 1, if (v2) STG_A(k2, 1, 0), -1);
    PHASE(1, 2, if (v3) STG_B(k3, 0, 1), -1);
    PHASE(1, 3, if (v3) STG_B(k3, 1, 1), (v3 ? NF : (v2 ? 0 : -1)));
  }

  const int crow0 = tm + wr * 128 + l4 * 4;
  const int ccol0 = tn + wc * (BN / 4) + l15;
#pragma unroll
  for (int m = 0; m < 8; ++m)
#pragma unroll
    for (int n = 0; n < NF; ++n) {
      const int col = ccol0 + n * 16;
#pragma unroll
      for (int r = 0; r < 4; ++r) {
        const int row = crow0 + m * 16 + r;
        float v = acc[m][n][r];
        if (EPI == 0) {
          ((float*)C0)[(size_t)row * 2560 + col] = v + bias[col];
        } else {
          if (col < 2560)
            ((ushort_t*)C0)[pkaddr(col, row, MROWS)] = f2bf(v + bias[col]);
          else
            ((ushort_t*)C1)[pkaddr(col - 2560, row, MROWS)] = f2bf(v);
        }
      }
    }
}

// ---------------- gate GEMM v4 (packed, A-resident 64x320, B-slab dbuf) ----------
// grid 1024: block = 64 rows x full head; 20 tn-steps of 32 cols.
// LDS 80KB (A 40KB resident + 2x20KB B) -> 2 blocks/CU. a-frags hoisted to regs.
// XCD map: 16 consecutive same-head blocks per XCD -> B-head (3.2MB) L2-resident.
__global__ __launch_bounds__(256, 2)
void gate_gemm(const ushort_t* __restrict__ A,      // xcbf packed [320][8192][8]
               const ushort_t* __restrict__ Bw,     // gwT packed [8*40][640][8]
               ushort_t* __restrict__ GX,           // T2 packed
               ushort_t* __restrict__ AAo,          // AA packed
               const float* __restrict__ gxb, const float* __restrict__ gab,
               const float* __restrict__ ctab, const int* __restrict__ seg) {
  __shared__ char smem[81920];   // A [40][64][16B] @0 ; B bufs @40960 + p*20480
  const int tid = threadIdx.x;
  const int lane = tid & 63, w = tid >> 6;     // 4 waves; wave w owns rows w*16..w*16+15
  const int l15 = lane & 15, l4 = lane >> 4;

  // decode: bid = x8 + 8*(16*z + t); tm_tile = t*8 + x8 (bijective)
  const int bid = blockIdx.x;
  const int x8 = bid & 7, s0 = bid >> 3;
  const int z = s0 >> 4;
  const int tm = ((s0 & 15) * 8 + x8) * 64;

  // stage A tile: 10 loads (1KB runs per slot)
#pragma unroll
  for (int u = 0; u < 10; ++u) {
    int lb = (u * 256 + tid) * 16;
    int slot = lb >> 10, m = (lb >> 4) & 63;
    async_load16((const char*)A + ((size_t)(z * 40 + slot) * MROWS + tm + m) * 16,
                 smem + lb);
  }
#define GSTG_B(S, BUF) do { \
  _Pragma("unroll") for (int u_ = 0; u_ < 5; ++u_) { \
    int lb_ = (u_ * 256 + tid) * 16; \
    int slot_ = lb_ >> 9, n_ = (lb_ >> 4) & 31; \
    async_load16((const char*)Bw + ((size_t)(z * 40 + slot_) * 640 + (S) * 32 + n_) * 16, \
                 smem + 40960 + (BUF) * 20480 + lb_); \
  } } while (0)

  GSTG_B(0, 0);
  asm volatile("s_waitcnt vmcnt(0)" ::: "memory");
  __builtin_amdgcn_sched_barrier(0);
  __builtin_amdgcn_s_barrier();

  // hoist a-frags (40 VGPR): af[kk] = A rows (w*16+l15), k-packet kk*4+l4
  short8 af[10];
#pragma unroll
  for (int kk = 0; kk < 10; ++kk)
    af[kk] = *(const short8*)(smem + (((kk * 4 + l4) * 64) + w * 16 + l15) * 16);

#pragma unroll 1
  for (int s = 0; s < 20; ++s) {
    const int p = s & 1;
    if (s < 19) {
      GSTG_B(s + 1, p ^ 1);
      asm volatile("s_waitcnt vmcnt(5)" ::: "memory");
    } else {
      asm volatile("s_waitcnt vmcnt(0)" ::: "memory");
    }
    __builtin_amdgcn_sched_barrier(0);
    __builtin_amdgcn_s_barrier();

    const char* Bb = smem + 40960 + p * 20480;
    f32x4 acc[2] = {};
#pragma unroll
    for (int kk = 0; kk < 10; ++kk) {
#pragma unroll
      for (int nf = 0; nf < 2; ++nf) {
        short8 bfr = *(const short8*)(Bb + (((kk * 4 + l4) * 32) + nf * 16 + l15) * 16);
        acc[nf] = __builtin_amdgcn_mfma_f32_16x16x32_bf16(af[kk], bfr, acc[nf], 0, 0, 0);
      }
    }

    // epilogue: rows tm + w*16 + l4*4 + r ; cols cbase + nf*16 + l15
    const bool isGX = (s < 10);
    const int cbase = (isGX ? s : s - 10) * 32;
#pragma unroll
    for (int nf = 0; nf < 2; ++nf) {
      const int cin = nf * 16 + l15;
      const int ch = cbase + cin;            // 0..319 in head
      const int gc = z * BW_ + ch;
#pragma unroll
      for (int r = 0; r < 4; ++r) {
        const int lrow = w * 16 + l4 * 4 + r;
        const int row = tm + lrow;
        if (isGX) {
          float v = acc[nf][r] + gxb[gc];
          float xc = bf2f(*(const ushort_t*)(smem + (((ch >> 3) * 64) + lrow) * 16 + (ch & 7) * 2));
          GX[pkaddr(gc, row, MROWS)] = f2bf(xc * sigmoidf_(v));
        } else {
          float v = acc[nf][r] + gab[gc];
          float la = ctab[gc] * sigmoidf_(v);
          float av = (seg[row] == 0) ? 0.f : expf(la);
          AAo[pkaddr(gc, row, MROWS)] = f2bf(av);
        }
      }
    }
    __builtin_amdgcn_sched_barrier(0);
    __builtin_amdgcn_s_barrier();   // all reads of buf p done before next stage
  }
#undef GSTG_B
}

// ---------------- conv (packed) + conv_state folded in tail blocks ----------------
__global__ void conv_pk(const ushort_t* __restrict__ xl, const float* __restrict__ convw,
                        const float* __restrict__ convb, ushort_t* __restrict__ xc,
                        const int* __restrict__ cidx, float* __restrict__ cs) {
  int i = blockIdx.x * blockDim.x + threadIdx.x;
  if (i < 320 * MROWS) {
    int m = i % MROWS;
    int p = i / MROWS;
    int t = m % LL;
    const ushort_t* pl = xl + (size_t)p * MROWS * 8;
    short8 v0 = {}, v1 = {}, v2 = {}, v3;
    v3 = *(const short8*)(pl + (size_t)m * 8);
    if (t >= 1) v2 = *(const short8*)(pl + (size_t)(m - 1) * 8);
    if (t >= 2) v1 = *(const short8*)(pl + (size_t)(m - 2) * 8);
    if (t >= 3) v0 = *(const short8*)(pl + (size_t)(m - 3) * 8);
    ushort_t o[8];
#pragma unroll
    for (int u = 0; u < 8; ++u) {
      int e = p * 8 + u;
      float4 wv = ((const float4*)convw)[e];
      float acc = convb[e];
      acc += wv.x * bf2f((ushort_t)v0[u]);
      acc += wv.y * bf2f((ushort_t)v1[u]);
      acc += wv.z * bf2f((ushort_t)v2[u]);
      acc += wv.w * bf2f((ushort_t)v3[u]);
      o[u] = f2bf(acc);
    }
    *(short8*)(xc + (size_t)p * MROWS * 8 + (size_t)m * 8) = *(short8*)o;
  } else {
    int j = i - 320 * MROWS;
    if (j >= BB * LRU_ * DCONV_) return;
    int e = (j / DCONV_) % LRU_;
    int b = j / (DCONV_ * LRU_);
    int idx = cidx[j];
    int ts = idx - (DCONV_ - 1);
    float v = 0.f;
    if (ts >= 0 && ts < LL) v = bf2f(xl[pkaddr(e, b * LL + ts, MROWS)]);
    cs[j] = v;
  }
}

// ---------------- chunked scan (packed inputs) ----------------
__global__ void scanA(const ushort_t* __restrict__ AA, const ushort_t* __restrict__ GX,
                      float* __restrict__ cA, float* __restrict__ cH) {
  int i = blockIdx.x * blockDim.x + threadIdx.x;
  if (i >= BB * NCH * LRU_) return;
  int e = i % LRU_;
  int c = (i / LRU_) % NCH;
  int b = i / (LRU_ * NCH);
  float Ap = 1.f, h = 0.f;
  size_t base = pkaddr(e, b * LL + c * CLEN, MROWS);
  for (int t = 0; t < CLEN; ++t) {
    size_t j = base + (size_t)t * 8;
    float a = bf2f(AA[j]);
    float nx = bf2f(GX[j]) * sqrtf(fmaxf(0.f, 1.f - a * a));
    Ap *= a;
    h = a * h + nx;
  }
  cA[i] = Ap; cH[i] = h;
}

__global__ void scanB(const float* __restrict__ cA, const float* __restrict__ cH,
                      float* __restrict__ hInit) {
  int i = blockIdx.x * blockDim.x + threadIdx.x;
  if (i >= BB * LRU_) return;
  int e = i % LRU_;
  int b = i / LRU_;
  float h = 0.f;
  for (int c = 0; c < NCH; ++c) {
    size_t j = ((size_t)b * NCH + c) * LRU_ + e;
    hInit[j] = h;
    h = cA[j] * h + cH[j];
  }
}

__global__ void scanC(const ushort_t* __restrict__ AA, const ushort_t* __restrict__ GXpre,
                      const float* __restrict__ hInit, const ushort_t* __restrict__ ybf,
                      const float* __restrict__ ybias, float* __restrict__ lastH) {
  int i = blockIdx.x * blockDim.x + threadIdx.x;
  if (i >= BB * NCH * LRU_) return;
  int e = i % LRU_;
  int c = (i / LRU_) % NCH;
  int b = i / (LRU_ * NCH);
  float h = hInit[i];
  float yb = ybias[e];
  ushort_t* pre = (ushort_t*)GXpre;
  size_t base = pkaddr(e, b * LL + c * CLEN, MROWS);
  for (int t = 0; t < CLEN; ++t) {
    size_t j = base + (size_t)t * 8;
    float a = bf2f(AA[j]);
    float nx = bf2f(GXpre[j]) * sqrtf(fmaxf(0.f, 1.f - a * a));
    h = a * h + nx;
    float yv = bf2f(ybf[j]) + yb;
    float g = 0.5f * yv * (1.f + erff(yv * 0.70710678118f));
    pre[j] = f2bf(h * g);
  }
  if (c == NCH - 1) lastH[(size_t)b * LRU_ + e] = h;
}

// ---------------- launch ----------------
extern "C" void kernel_launch(void* const* d_in, const int* in_sizes, int n_in,
                              void* d_out, int out_size, void* d_ws, size_t ws_size,
                              hipStream_t stream) {
  const float* x     = (const float*)d_in[0];
  const int*   seg   = (const int*)d_in[1];
  const int*   cidx  = (const int*)d_in[2];
  const float* Wx    = (const float*)d_in[3];
  const float* bx    = (const float*)d_in[4];
  const float* Wy    = (const float*)d_in[5];
  const float* convw = (const float*)d_in[6];
  const float* convb = (const float*)d_in[7];
  const float* gxw   = (const float*)d_in[8];
  const float* gxb   = (const float*)d_in[9];
  const float* gaw   = (const float*)d_in[10];
  const float* gab   = (const float*)d_in[11];
  const float* apar  = (const float*)d_in[12];
  const float* ybias = (const float*)d_in[13];
  const float* Wout  = (const float*)d_in[14];
  const float* bout  = (const float*)d_in[15];

  float* out    = (float*)d_out;
  float* cs_out = out + (size_t)MROWS * WIDTH_;
  float* lh_out = cs_out + (size_t)BB * LRU_ * DCONV_;

  ushort_t* ybf = (ushort_t*)d_out;                               // packed, 41.94 MB
  ushort_t* AA  = (ushort_t*)((char*)d_out + (size_t)41943040);   // packed, 41.94 MB

  const size_t SZ_BIG = (size_t)MROWS * LRU_ * 2;       // 41,943,040
  const size_t SZ_WC  = (size_t)(2 * LRU_) * WIDTH_ * 2;// 26,214,400
  const size_t SZ_GW  = (size_t)HEADS_ * 640 * BW_ * 2; // 3,276,800
  const size_t SZ_SM  = (size_t)BB * NCH * LRU_ * 4;    // 1,310,720
  size_t need = SZ_BIG * 3 + SZ_WC + SZ_GW + 10240 + SZ_SM * 3;
  if (ws_size < need) return;

  char* p = (char*)d_ws;
  ushort_t* xpk   = (ushort_t*)p; p += SZ_BIG;
  ushort_t* wpk   = (ushort_t*)p; p += SZ_WC;
  ushort_t* T2    = (ushort_t*)p; p += SZ_BIG;
  ushort_t* xcbf  = (ushort_t*)p; p += SZ_BIG;
  ushort_t* gwT   = (ushort_t*)p; p += SZ_GW;
  float*    ctab  = (float*)p;    p += 10240;
  float*    cA    = (float*)p;    p += SZ_SM;
  float*    cH    = (float*)p;    p += SZ_SM;
  float*    hInit = (float*)p;    p += SZ_SM;
  ushort_t* woutpk = wpk;

  const int BLK = 256;
  // transpose-pack x, then [Wx|Wy] in one z=2 launch
  tp_pack<<<dim3(MROWS / 64, WIDTH_ / 64, 1), 256, 0, stream>>>(x, nullptr, xpk, MROWS, WIDTH_, MROWS, 0);
  tp_pack<<<dim3(LRU_ / 64, WIDTH_ / 64, 2), 256, 0, stream>>>(Wx, Wy, wpk, LRU_, WIDTH_, 2 * LRU_, 0);

  // fused: [xl | y] = x @ [Wx;Wy]^T   (N=5120, BN=256, 640 blocks) -> T2, ybf
  gemm_pk<1, 256><<<640, 512, 0, stream>>>(xpk, wpk, 2 * LRU_, T2, ybf, bx);

  // Wout packed into wpk region (dead after GEMM1; stream-ordered)
  tp_pack<<<dim3(LRU_ / 64, WIDTH_ / 64, 1), 256, 0, stream>>>(Wout, nullptr, woutpk, WIDTH_, LRU_, WIDTH_, 0);

  conv_pk<<<(320 * MROWS + BB * LRU_ * DCONV_ + BLK - 1) / BLK, BLK, 0, stream>>>(
      T2, convw, convb, xcbf, cidx, cs_out);

  prep_kernel<<<(2 * HEADS_ * BW_ * BW_ + LRU_ + BLK - 1) / BLK, BLK, 0, stream>>>(
      gxw, gaw, gwT, apar, ctab);

  // fused gate GEMM v4 (A-resident): GX -> T2 (over dead xl), AA -> d_out scratch
  gate_gemm<<<1024, BLK, 0, stream>>>(xcbf, gwT, T2, AA, gxb, gab, ctab, seg);

  scanA<<<(BB * NCH * LRU_ + BLK - 1) / BLK, BLK, 0, stream>>>(AA, T2, cA, cH);
  scanB<<<(BB * LRU_ + BLK - 1) / BLK, BLK, 0, stream>>>(cA, cH, hInit);
  scanC<<<(BB * NCH * LRU_ + BLK - 1) / BLK, BLK, 0, stream>>>(AA, T2, hInit, ybf, ybias, lh_out);

  // out = pre @ Wout^T + bout  (N=2560, BN=320, 256 blocks = 1 round), f32
  gemm_pk<0, 320><<<256, 512, 0, stream>>>(T2, woutpk, WIDTH_, out, nullptr, bout);
}

// Round 15
// 550.776 us; speedup vs baseline: 1.0787x; 1.0787x over previous
//
#include <hip/hip_runtime.h>
#include <hip/hip_bf16.h>

#define WIDTH_ 2560
#define LRU_   2560
#define HEADS_ 8
#define BW_    320
#define DCONV_ 4
#define BB     4
#define LL     2048
#define MROWS  (BB*LL)          // 8192
#define NCH    32               // scan chunks
#define CLEN   (LL/NCH)         // 64

typedef unsigned short ushort_t;
typedef __attribute__((ext_vector_type(8))) short short8;
typedef __attribute__((ext_vector_type(4))) float f32x4;

__device__ __forceinline__ unsigned short f2bf(float f) {
  union { float f; unsigned u; } v; v.f = f;
  unsigned r = v.u + 0x7fffu + ((v.u >> 16) & 1u);
  return (unsigned short)(r >> 16);
}
__device__ __forceinline__ float bf2f(unsigned short h) {
  union { unsigned u; float f; } v; v.u = ((unsigned)h) << 16;
  return v.f;
}
__device__ __forceinline__ void async_load16(const void* g, void* l) {
  __builtin_amdgcn_global_load_lds(
      (const __attribute__((address_space(1))) unsigned*)g,
      (__attribute__((address_space(3))) unsigned*)l, 16, 0, 0);
}
__device__ __forceinline__ float sigmoidf_(float x) {
  return 1.f / (1.f + __expf(-x));
}
// packed [C/8][PL][8] address (ushort units)
__device__ __forceinline__ size_t pkaddr(int e, int m, int PL) {
  return ((size_t)(e >> 3) * PL + m) * 8 + (e & 7);
}

// ------------- transpose-pack: f32 [R][C] -> bf16 packed [C/8][PL][8] @ row RO -----
// src2 != nullptr: blockIdx.z selects {src, src2} with RO = z*R (Wx/Wy merge)
__global__ void tp_pack(const float* __restrict__ src, const float* __restrict__ src2,
                        ushort_t* __restrict__ dst, int R, int C, int PL, int RO) {
  __shared__ float tile[64][65];
  const int z = blockIdx.z;
  const float* s = (z == 0) ? src : src2;
  const int ro = RO + z * R;
  const int r0 = blockIdx.x * 64, c0 = blockIdx.y * 64;
  const int t = threadIdx.x;
#pragma unroll
  for (int it = 0; it < 4; ++it) {
    int row = it * 16 + (t >> 4);
    int col = (t & 15) * 4;
    *(float4*)&tile[row][col] = *(const float4*)&s[(size_t)(r0 + row) * C + c0 + col];
  }
  __syncthreads();
#pragma unroll
  for (int it = 0; it < 2; ++it) {
    int c8 = it * 4 + (t >> 6);     // 0..7
    int m  = t & 63;
    ushort_t o[8];
#pragma unroll
    for (int j = 0; j < 8; ++j) o[j] = f2bf(tile[m][c8 * 8 + j]);
    *(short8*)&dst[((size_t)(c0 / 8 + c8) * PL + ro + r0 + m) * 8] = *(short8*)o;
  }
}

// prep: gate weights pack (both) + ctab.  dst[h*40+k>>3][RO+n][k&7] = w[h][k][n]
__global__ void prep_kernel(const float* __restrict__ gxw, const float* __restrict__ gaw,
                            ushort_t* __restrict__ dst,
                            const float* __restrict__ apar, float* __restrict__ ctab) {
  const int n_ = HEADS_ * BW_ * BW_;
  int i = blockIdx.x * blockDim.x + threadIdx.x;
  if (i < 2 * n_) {
    const float* w = (i < n_) ? gxw : gaw;
    int RO = (i < n_) ? 0 : BW_;
    int j = (i < n_) ? i : i - n_;
    int n = j % BW_;
    int k = (j / BW_) % BW_;
    int h = j / (BW_ * BW_);
    dst[((size_t)(h * 40 + (k >> 3)) * 640 + RO + n) * 8 + (k & 7)] =
        f2bf(w[((size_t)h * BW_ + k) * BW_ + n]);
  } else if (i < 2 * n_ + LRU_) {
    int e = i - 2 * n_;
    float ap = apar[e];
    float sp = (ap > 15.f) ? ap : log1pf(expf(ap));
    ctab[e] = -8.f * sp;
  }
}

// ============ 256xBN GEMM, packed operands, 8-phase schedule (FROZEN) ============
#define STG_A(KT, H, BUF) do { \
  _Pragma("unroll") for (int u_ = 0; u_ < 2; ++u_) \
    async_load16(Ach + aoff[u_] + (size_t)(KT) * aKt + (H) * 2048, \
                 smem + ((BUF) * 2 + (H)) * 16384 + ldst[u_]); } while (0)
#define STG_B(KT, PART, BUF) do { \
  _Pragma("unroll") for (int u_ = (PART) ? 2 : 0; u_ < ((PART) ? NF : 2); ++u_) \
    async_load16(Bch + boff[u_] + (size_t)(KT) * bKt, \
                 smem + 65536 + (BUF) * BREG + bldst[u_]); } while (0)

#define PHASE(BUF, Q, STAGE_STMT, VMN) do { \
  __builtin_amdgcn_sched_barrier(0); \
  const char* Ah_ = smem + ((BUF) * 2 + wr) * 16384; \
  const char* Bh_ = smem + 65536 + (BUF) * BREG; \
  if ((Q) == 0) { \
    _Pragma("unroll") for (int nf = 0; nf < NF; ++nf) \
      _Pragma("unroll") for (int s = 0; s < 2; ++s) \
        bfr[nf][s] = *(const short8*)(Bh_ + (((s * 4 + l4) * BN) + wc * (BN / 4) + nf * 16 + l15) * 16); \
  } \
  short8 a_[2][2]; \
  _Pragma("unroll") for (int mm = 0; mm < 2; ++mm) \
    _Pragma("unroll") for (int s = 0; s < 2; ++s) \
      a_[mm][s] = *(const short8*)(Ah_ + ((s * 4 + l4) * 128 + ((Q) * 2 + mm) * 16 + l15) * 16); \
  STAGE_STMT; \
  __builtin_amdgcn_sched_barrier(0); \
  __builtin_amdgcn_s_barrier(); \
  asm volatile("s_waitcnt lgkmcnt(0)" ::: "memory"); \
  __builtin_amdgcn_sched_barrier(0); \
  __builtin_amdgcn_s_setprio(1); \
  _Pragma("unroll") for (int mm = 0; mm < 2; ++mm) \
    _Pragma("unroll") for (int nf = 0; nf < NF; ++nf) \
      _Pragma("unroll") for (int s = 0; s < 2; ++s) \
        acc[(Q) * 2 + mm][nf] = __builtin_amdgcn_mfma_f32_16x16x32_bf16( \
            a_[mm][s], bfr[nf][s], acc[(Q) * 2 + mm][nf], 0, 0, 0); \
  __builtin_amdgcn_s_setprio(0); \
  if ((VMN) == 5)      asm volatile("s_waitcnt vmcnt(5)" ::: "memory"); \
  else if ((VMN) == 4) asm volatile("s_waitcnt vmcnt(4)" ::: "memory"); \
  else if ((VMN) == 0) asm volatile("s_waitcnt vmcnt(0)" ::: "memory"); \
  __builtin_amdgcn_sched_barrier(0); \
  __builtin_amdgcn_s_barrier(); \
} while (0)

// EPI 0: f32 row-major store + bias   EPI 1: split packed bf16 (col<2560->C0+bias, else C1)
template<int EPI, int BN>
__global__ __launch_bounds__(512, 2)
void gemm_pk(const ushort_t* __restrict__ A,
             const ushort_t* __restrict__ B, int NPL,
             void* __restrict__ C0, void* __restrict__ C1,
             const float* __restrict__ bias) {
  constexpr int NF = BN / 64;
  constexpr int BREG = BN * 128;
  __shared__ char smem[65536 + 2 * BREG];
  const int tid = threadIdx.x;
  const int lane = tid & 63, w = tid >> 6;
  const int wr = w >> 2, wc = w & 3;
  const int l15 = lane & 15, l4 = lane >> 4;

  const int nblk = gridDim.x;
  const int TN = nblk >> 5;
  const int x8 = blockIdx.x & 7, c = blockIdx.x >> 3;
  const int tm = (x8 * 4 + c / TN) * 256;
  const int tn = (c % TN) * BN;

  const char* Ach = (const char*)A;
  const char* Bch = (const char*)B;
  const size_t aKt = (size_t)8 * MROWS * 16;
  const size_t bKt = (size_t)8 * NPL * 16;

  size_t aoff[2]; int ldst[2];
#pragma unroll
  for (int u = 0; u < 2; ++u) {
    int lb = (u * 512 + tid) * 16;
    int slot = lb >> 11, m = (lb >> 4) & 127;
    aoff[u] = ((size_t)slot * MROWS + tm + m) * 16;
    ldst[u] = lb;
  }
  size_t boff[NF]; int bldst[NF];
#pragma unroll
  for (int u = 0; u < NF; ++u) {
    int lb = (u * 512 + tid) * 16;
    int slot = lb / (BN * 16), n = (lb - slot * (BN * 16)) >> 4;
    boff[u] = ((size_t)slot * NPL + tn + n) * 16;
    bldst[u] = lb;
  }

  f32x4 acc[8][NF] = {};
  short8 bfr[NF][2];

  STG_B(0, 0, 0); STG_B(0, 1, 0);
  STG_A(0, 0, 0); STG_A(0, 1, 0);
  STG_B(1, 0, 1); STG_B(1, 1, 1);
  if (NF == 5) asm volatile("s_waitcnt vmcnt(5)" ::: "memory");
  else         asm volatile("s_waitcnt vmcnt(4)" ::: "memory");
  __builtin_amdgcn_sched_barrier(0);
  __builtin_amdgcn_s_barrier();

#pragma unroll 1
  for (int i = 0; i < 20; ++i) {
    const int k1 = 2 * i + 1, k2 = 2 * i + 2, k3 = 2 * i + 3;
    const bool v2 = (k2 < 40), v3 = (k3 < 40);
    PHASE(0, 0, STG_A(k1, 0, 1), -1);
    PHASE(0, 1, STG_A(k1, 1, 1), -1);
    PHASE(0, 2, if (v2) STG_B(k2, 0, 0), -1);
    PHASE(0, 3, if (v2) STG_B(k2, 1, 0), (v2 ? NF : 0));
    PHASE(1, 0, if (v2) STG_A(k2, 0, 0), -1);
    PHASE(1, 1, if (v2) STG_A(k2, 1, 0), -1);
    PHASE(1, 2, if (v3) STG_B(k3, 0, 1), -1);
    PHASE(1, 3, if (v3) STG_B(k3, 1, 1), (v3 ? NF : (v2 ? 0 : -1)));
  }

  const int crow0 = tm + wr * 128 + l4 * 4;
  const int ccol0 = tn + wc * (BN / 4) + l15;
#pragma unroll
  for (int m = 0; m < 8; ++m)
#pragma unroll
    for (int n = 0; n < NF; ++n) {
      const int col = ccol0 + n * 16;
#pragma unroll
      for (int r = 0; r < 4; ++r) {
        const int row = crow0 + m * 16 + r;
        float v = acc[m][n][r];
        if (EPI == 0) {
          ((float*)C0)[(size_t)row * 2560 + col] = v + bias[col];
        } else {
          if (col < 2560)
            ((ushort_t*)C0)[pkaddr(col, row, MROWS)] = f2bf(v + bias[col]);
          else
            ((ushort_t*)C1)[pkaddr(col - 2560, row, MROWS)] = f2bf(v);
        }
      }
    }
}

// ---------------- gate GEMM v1.6 (packed): BM=128 BN=64, 2-buffer counted vmcnt ---
// per head z: C' = xc_head @ gwT_z^T ; gwT packed [z*40+k8][640][8]
// LDS 24KB (2 bufs x 12KB) -> high occupancy. XCD-chunked 1D grid (5120 blocks).
__global__ __launch_bounds__(256, 2)
void gate_gemm(const ushort_t* __restrict__ A,      // xcbf packed [320][8192][8]
               const ushort_t* __restrict__ Bw,     // gwT packed
               ushort_t* __restrict__ GX,           // T2 packed
               ushort_t* __restrict__ AAo,          // AA packed
               const float* __restrict__ gxb, const float* __restrict__ gab,
               const float* __restrict__ ctab, const int* __restrict__ seg) {
  constexpr int BM = 128, NF = 2;
  __shared__ char smem[24576];
  const int tid = threadIdx.x;
  const int w = tid >> 6, lane = tid & 63;
  const int wr = w >> 1, wc = w & 1;
  const int l15 = lane & 15, l4 = lane >> 4;

  const int bid = blockIdx.x;          // 0..5119
  const int x8 = bid & 7;
  const int s = bid >> 3;              // 0..639 per XCD
  const int member = s % 10;           // tn step
  const int g = (s / 10) * 8 + x8;     // 0..511 group id
  const int tm = (g & 63) * BM;
  const int z = g >> 6;
  const int tn = member * 64;          // 0..576 within head's 640

  const char* aS[2]; int lda_[2];
#pragma unroll
  for (int u = 0; u < 2; ++u) {
    int lb = (u * 256 + tid) * 16;
    int slot = lb >> 11, m = (lb >> 4) & 127;
    aS[u] = (const char*)A + ((size_t)(z * 40 + slot) * MROWS + tm + m) * 16;
    lda_[u] = lb;
  }
  const char* bS; int ldb_;
  {
    int lb = tid * 16;
    int slot = lb >> 10, n = (lb >> 4) & 63;
    bS = (const char*)Bw + ((size_t)(z * 40 + slot) * 640 + tn + n) * 16;
    ldb_ = 8192 + lb;
  }
  const size_t aStep = (size_t)4 * MROWS * 16;
  const size_t bStep = (size_t)4 * 640 * 16;

#define GSTG(KT, BUF) do { \
  _Pragma("unroll") for (int u_ = 0; u_ < 2; ++u_) \
    async_load16(aS[u_] + (size_t)(KT) * aStep, smem + (BUF) * 12288 + lda_[u_]); \
  async_load16(bS + (size_t)(KT) * bStep, smem + (BUF) * 12288 + ldb_); \
} while (0)

  f32x4 acc[4][NF] = {};
  const int aRd = l4 * 2048 + (wr * 64 + l15) * 16;
  const int bRd = 8192 + l4 * 1024 + (wc * 32 + l15) * 16;

  GSTG(0, 0);
#pragma unroll 1
  for (int kt = 0; kt < 10; ++kt) {
    const int p = kt & 1;
    if (kt < 9) {
      GSTG(kt + 1, p ^ 1);
      asm volatile("s_waitcnt vmcnt(3)" ::: "memory");
    } else {
      asm volatile("s_waitcnt vmcnt(0)" ::: "memory");
    }
    __builtin_amdgcn_sched_barrier(0);
    __builtin_amdgcn_s_barrier();
    const char* buf = smem + p * 12288;
    short8 af[4], bfr[NF];
#pragma unroll
    for (int mf = 0; mf < 4; ++mf)
      af[mf] = *(const short8*)(buf + aRd + mf * 256);
#pragma unroll
    for (int nf = 0; nf < NF; ++nf)
      bfr[nf] = *(const short8*)(buf + bRd + nf * 256);
#pragma unroll
    for (int mf = 0; mf < 4; ++mf)
#pragma unroll
      for (int nf = 0; nf < NF; ++nf)
        acc[mf][nf] = __builtin_amdgcn_mfma_f32_16x16x32_bf16(af[mf], bfr[nf], acc[mf][nf], 0, 0, 0);
    __builtin_amdgcn_sched_barrier(0);
    __builtin_amdgcn_s_barrier();
  }
#undef GSTG

  const int crow0 = tm + wr * 64 + l4 * 4;
  const int ccol0 = tn + wc * 32 + l15;
#pragma unroll
  for (int mf = 0; mf < 4; ++mf) {
#pragma unroll
    for (int nf = 0; nf < NF; ++nf) {
      const int cih = ccol0 + nf * 16;     // 0..639 within head
#pragma unroll
      for (int r = 0; r < 4; ++r) {
        const int row = crow0 + mf * 16 + r;
        if (cih < BW_) {
          const int gc = z * BW_ + cih;
          float v = acc[mf][nf][r] + gxb[gc];
          float xc = bf2f(A[pkaddr(gc, row, MROWS)]);
          GX[pkaddr(gc, row, MROWS)] = f2bf(xc * sigmoidf_(v));
        } else {
          const int gc = z * BW_ + cih - BW_;
          float v = acc[mf][nf][r] + gab[gc];
          float la = ctab[gc] * sigmoidf_(v);
          float av = (seg[row] == 0) ? 0.f : expf(la);
          AAo[pkaddr(gc, row, MROWS)] = f2bf(av);
        }
      }
    }
  }
}

// ---------------- conv (packed) + conv_state folded in tail blocks ----------------
__global__ void conv_pk(const ushort_t* __restrict__ xl, const float* __restrict__ convw,
                        const float* __restrict__ convb, ushort_t* __restrict__ xc,
                        const int* __restrict__ cidx, float* __restrict__ cs) {
  int i = blockIdx.x * blockDim.x + threadIdx.x;
  if (i < 320 * MROWS) {
    int m = i % MROWS;
    int p = i / MROWS;
    int t = m % LL;
    const ushort_t* pl = xl + (size_t)p * MROWS * 8;
    short8 v0 = {}, v1 = {}, v2 = {}, v3;
    v3 = *(const short8*)(pl + (size_t)m * 8);
    if (t >= 1) v2 = *(const short8*)(pl + (size_t)(m - 1) * 8);
    if (t >= 2) v1 = *(const short8*)(pl + (size_t)(m - 2) * 8);
    if (t >= 3) v0 = *(const short8*)(pl + (size_t)(m - 3) * 8);
    ushort_t o[8];
#pragma unroll
    for (int u = 0; u < 8; ++u) {
      int e = p * 8 + u;
      float4 wv = ((const float4*)convw)[e];
      float acc = convb[e];
      acc += wv.x * bf2f((ushort_t)v0[u]);
      acc += wv.y * bf2f((ushort_t)v1[u]);
      acc += wv.z * bf2f((ushort_t)v2[u]);
      acc += wv.w * bf2f((ushort_t)v3[u]);
      o[u] = f2bf(acc);
    }
    *(short8*)(xc + (size_t)p * MROWS * 8 + (size_t)m * 8) = *(short8*)o;
  } else {
    int j = i - 320 * MROWS;
    if (j >= BB * LRU_ * DCONV_) return;
    int e = (j / DCONV_) % LRU_;
    int b = j / (DCONV_ * LRU_);
    int idx = cidx[j];
    int ts = idx - (DCONV_ - 1);
    float v = 0.f;
    if (ts >= 0 && ts < LL) v = bf2f(xl[pkaddr(e, b * LL + ts, MROWS)]);
    cs[j] = v;
  }
}

// ---------------- chunked scan (packed inputs) ----------------
__global__ void scanA(const ushort_t* __restrict__ AA, const ushort_t* __restrict__ GX,
                      float* __restrict__ cA, float* __restrict__ cH) {
  int i = blockIdx.x * blockDim.x + threadIdx.x;
  if (i >= BB * NCH * LRU_) return;
  int e = i % LRU_;
  int c = (i / LRU_) % NCH;
  int b = i / (LRU_ * NCH);
  float Ap = 1.f, h = 0.f;
  size_t base = pkaddr(e, b * LL + c * CLEN, MROWS);
  for (int t = 0; t < CLEN; ++t) {
    size_t j = base + (size_t)t * 8;
    float a = bf2f(AA[j]);
    float nx = bf2f(GX[j]) * sqrtf(fmaxf(0.f, 1.f - a * a));
    Ap *= a;
    h = a * h + nx;
  }
  cA[i] = Ap; cH[i] = h;
}

__global__ void scanB(const float* __restrict__ cA, const float* __restrict__ cH,
                      float* __restrict__ hInit) {
  int i = blockIdx.x * blockDim.x + threadIdx.x;
  if (i >= BB * LRU_) return;
  int e = i % LRU_;
  int b = i / LRU_;
  float h = 0.f;
  for (int c = 0; c < NCH; ++c) {
    size_t j = ((size_t)b * NCH + c) * LRU_ + e;
    hInit[j] = h;
    h = cA[j] * h + cH[j];
  }
}

__global__ void scanC(const ushort_t* __restrict__ AA, const ushort_t* __restrict__ GXpre,
                      const float* __restrict__ hInit, const ushort_t* __restrict__ ybf,
                      const float* __restrict__ ybias, float* __restrict__ lastH) {
  int i = blockIdx.x * blockDim.x + threadIdx.x;
  if (i >= BB * NCH * LRU_) return;
  int e = i % LRU_;
  int c = (i / LRU_) % NCH;
  int b = i / (LRU_ * NCH);
  float h = hInit[i];
  float yb = ybias[e];
  ushort_t* pre = (ushort_t*)GXpre;
  size_t base = pkaddr(e, b * LL + c * CLEN, MROWS);
  for (int t = 0; t < CLEN; ++t) {
    size_t j = base + (size_t)t * 8;
    float a = bf2f(AA[j]);
    float nx = bf2f(GXpre[j]) * sqrtf(fmaxf(0.f, 1.f - a * a));
    h = a * h + nx;
    float yv = bf2f(ybf[j]) + yb;
    float g = 0.5f * yv * (1.f + erff(yv * 0.70710678118f));
    pre[j] = f2bf(h * g);
  }
  if (c == NCH - 1) lastH[(size_t)b * LRU_ + e] = h;
}

// ---------------- launch ----------------
extern "C" void kernel_launch(void* const* d_in, const int* in_sizes, int n_in,
                              void* d_out, int out_size, void* d_ws, size_t ws_size,
                              hipStream_t stream) {
  const float* x     = (const float*)d_in[0];
  const int*   seg   = (const int*)d_in[1];
  const int*   cidx  = (const int*)d_in[2];
  const float* Wx    = (const float*)d_in[3];
  const float* bx    = (const float*)d_in[4];
  const float* Wy    = (const float*)d_in[5];
  const float* convw = (const float*)d_in[6];
  const float* convb = (const float*)d_in[7];
  const float* gxw   = (const float*)d_in[8];
  const float* gxb   = (const float*)d_in[9];
  const float* gaw   = (const float*)d_in[10];
  const float* gab   = (const float*)d_in[11];
  const float* apar  = (const float*)d_in[12];
  const float* ybias = (const float*)d_in[13];
  const float* Wout  = (const float*)d_in[14];
  const float* bout  = (const float*)d_in[15];

  float* out    = (float*)d_out;
  float* cs_out = out + (size_t)MROWS * WIDTH_;
  float* lh_out = cs_out + (size_t)BB * LRU_ * DCONV_;

  ushort_t* ybf = (ushort_t*)d_out;                               // packed, 41.94 MB
  ushort_t* AA  = (ushort_t*)((char*)d_out + (size_t)41943040);   // packed, 41.94 MB

  const size_t SZ_BIG = (size_t)MROWS * LRU_ * 2;       // 41,943,040
  const size_t SZ_WC  = (size_t)(2 * LRU_) * WIDTH_ * 2;// 26,214,400
  const size_t SZ_GW  = (size_t)HEADS_ * 640 * BW_ * 2; // 3,276,800
  const size_t SZ_SM  = (size_t)BB * NCH * LRU_ * 4;    // 1,310,720
  size_t need = SZ_BIG * 3 + SZ_WC + SZ_GW + 10240 + SZ_SM * 3;
  if (ws_size < need) return;

  char* p = (char*)d_ws;
  ushort_t* xpk   = (ushort_t*)p; p += SZ_BIG;
  ushort_t* wpk   = (ushort_t*)p; p += SZ_WC;
  ushort_t* T2    = (ushort_t*)p; p += SZ_BIG;
  ushort_t* xcbf  = (ushort_t*)p; p += SZ_BIG;
  ushort_t* gwT   = (ushort_t*)p; p += SZ_GW;
  float*    ctab  = (float*)p;    p += 10240;
  float*    cA    = (float*)p;    p += SZ_SM;
  float*    cH    = (float*)p;    p += SZ_SM;
  float*    hInit = (float*)p;    p += SZ_SM;
  ushort_t* woutpk = wpk;

  const int BLK = 256;
  // transpose-pack x, then [Wx|Wy] in one z=2 launch
  tp_pack<<<dim3(MROWS / 64, WIDTH_ / 64, 1), 256, 0, stream>>>(x, nullptr, xpk, MROWS, WIDTH_, MROWS, 0);
  tp_pack<<<dim3(LRU_ / 64, WIDTH_ / 64, 2), 256, 0, stream>>>(Wx, Wy, wpk, LRU_, WIDTH_, 2 * LRU_, 0);

  // fused: [xl | y] = x @ [Wx;Wy]^T   (N=5120, BN=256, 640 blocks) -> T2, ybf
  gemm_pk<1, 256><<<640, 512, 0, stream>>>(xpk, wpk, 2 * LRU_, T2, ybf, bx);

  // Wout packed into wpk region (dead after GEMM1; stream-ordered)
  tp_pack<<<dim3(LRU_ / 64, WIDTH_ / 64, 1), 256, 0, stream>>>(Wout, nullptr, woutpk, WIDTH_, LRU_, WIDTH_, 0);

  conv_pk<<<(320 * MROWS + BB * LRU_ * DCONV_ + BLK - 1) / BLK, BLK, 0, stream>>>(
      T2, convw, convb, xcbf, cidx, cs_out);

  prep_kernel<<<(2 * HEADS_ * BW_ * BW_ + LRU_ + BLK - 1) / BLK, BLK, 0, stream>>>(
      gxw, gaw, gwT, apar, ctab);

  // fused gate GEMM v1.6 (XCD-chunked): GX -> T2 (over dead xl), AA -> d_out scratch
  gate_gemm<<<5120, BLK, 0, stream>>>(xcbf, gwT, T2, AA, gxb, gab, ctab, seg);

  scanA<<<(BB * NCH * LRU_ + BLK - 1) / BLK, BLK, 0, stream>>>(AA, T2, cA, cH);
  scanB<<<(BB * LRU_ + BLK - 1) / BLK, BLK, 0, stream>>>(cA, cH, hInit);
  scanC<<<(BB * NCH * LRU_ + BLK - 1) / BLK, BLK, 0, stream>>>(AA, T2, hInit, ybf, ybias, lh_out);

  // out = pre @ Wout^T + bout  (N=2560, BN=320, 256 blocks = 1 round), f32
  gemm_pk<0, 320><<<256, 512, 0, stream>>>(T2, woutpk, WIDTH_, out, nullptr, bout);
}